// Round 1
// baseline (1298.922 us; speedup 1.0000x reference)
//
#include <hip/hip_runtime.h>
#include <math.h>

namespace {

constexpr int C_   = 128;
constexpr int C2_  = 256;   // 2*C
constexpr int NH_  = 9;
constexpr int H_   = 4;
constexpr int DH_  = 32;
constexpr int S_   = 16384;
constexpr int NTOK = 65536; // B*V*T*S

__device__ __forceinline__ float gelu_tanh(float v) {
    const float k0 = 0.7978845608028654f; // sqrt(2/pi)
    float u = k0 * (v + 0.044715f * v * v * v);
    return 0.5f * v * (1.0f + tanhf(u));
}

// ---------------------------------------------------------------------------
// Kernel 1: xe = LayerNorm(x) * g + b   (per-token over C=128)
// 256 threads = 2 token groups of 128 threads each.
// ---------------------------------------------------------------------------
__global__ __launch_bounds__(256) void ln1_kernel(
    const float* __restrict__ x,
    const float* __restrict__ g,
    const float* __restrict__ b,
    float* __restrict__ xe)
{
    const int grp = threadIdx.x >> 7;   // 0..1
    const int c   = threadIdx.x & 127;
    const int tok = blockIdx.x * 2 + grp;
    if (tok >= NTOK) return;

    __shared__ float sred[2][2][2];

    float v = x[(size_t)tok * C_ + c];
    float s0 = v, s1 = v * v;
    #pragma unroll
    for (int off = 32; off; off >>= 1) {
        s0 += __shfl_down(s0, off, 64);
        s1 += __shfl_down(s1, off, 64);
    }
    const int wig = (threadIdx.x >> 6) & 1;
    if ((threadIdx.x & 63) == 0) { sred[grp][wig][0] = s0; sred[grp][wig][1] = s1; }
    __syncthreads();
    float sum = sred[grp][0][0] + sred[grp][1][0];
    float sq  = sred[grp][0][1] + sred[grp][1][1];
    float mean = sum * (1.0f / C_);
    float var  = sq  * (1.0f / C_) - mean * mean;
    float inv  = rsqrtf(var + 1e-5f);
    xe[(size_t)tok * C_ + c] = (v - mean) * inv * g[c] + b[c];
}

// ---------------------------------------------------------------------------
// Kernel 2: everything else, fully fused per token.
// 256 threads = 2 token groups of 128 threads.
// ---------------------------------------------------------------------------
__global__ __launch_bounds__(256) void token_kernel(
    const float* __restrict__ x,
    const int*   __restrict__ adjc,
    const unsigned char* __restrict__ mask,
    const float* __restrict__ Wq,
    const float* __restrict__ Wkv,
    const float* __restrict__ b_kv,
    const float* __restrict__ W_nh,
    const float* __restrict__ W_ao,
    const float* __restrict__ ln2_g,
    const float* __restrict__ ln2_b,
    const float* __restrict__ W1,
    const float* __restrict__ b1,
    const float* __restrict__ W2,
    const float* __restrict__ b2,
    const float* __restrict__ gamma,
    const float* __restrict__ Wout,
    const float* __restrict__ xe,
    float* __restrict__ out)
{
    const int grp = threadIdx.x >> 7;   // 0..1
    const int c   = threadIdx.x & 127;
    const int tok = blockIdx.x * 2 + grp;
    const int bvt = tok >> 14;          // tok / S
    const int s   = tok & (S_ - 1);     // tok % S

    __shared__ float sxe[2][C_];        // xe of this token
    __shared__ float sq_[2][C_];        // q
    __shared__ float sxn[2][NH_][C_];   // gathered neighbor xe
    __shared__ float sk_[2][NH_][C_];   // K after mix
    __shared__ float sv_[2][NH_][C_];   // V after mix
    __shared__ float sat[2][H_][NH_];   // scores -> attn
    __shared__ float sbuf[2][C2_];      // o (128), later h (256)
    __shared__ float svec[2][C_];       // xm, later y
    __shared__ float sred[2][2][2];
    __shared__ int   sidx[2][NH_];
    __shared__ float smsk[2][NH_];
    __shared__ float swnh[NH_ * NH_];   // W_nh, shared by both groups

    const float xc = x[(size_t)tok * C_ + c];  // original x for residual
    sxe[grp][c] = xe[(size_t)tok * C_ + c];
    if (threadIdx.x < NH_ * NH_) swnh[threadIdx.x] = W_nh[threadIdx.x];
    if (c < NH_) {
        int nb = adjc[s * NH_ + c];
        int gidx = bvt * S_ + nb;
        sidx[grp][c] = gidx;
        smsk[grp][c] = mask[gidx] ? 1.0f : 0.0f;
    }
    __syncthreads();

    // ---- gather neighbor xe rows ----
    #pragma unroll
    for (int n = 0; n < NH_; ++n) {
        sxn[grp][n][c] = xe[(size_t)sidx[grp][n] * C_ + c];
    }
    // ---- q = xe @ Wq ----
    {
        float acc = 0.0f;
        #pragma unroll 8
        for (int cc = 0; cc < C_; ++cc) acc += sxe[grp][cc] * Wq[cc * C_ + c];
        sq_[grp][c] = acc;
    }
    __syncthreads();

    // ---- kv = gathered @ Wkv + b_kv ; thread owns K col c and V col c ----
    float ka[NH_], va[NH_];
    {
        const float bk = b_kv[c];
        const float bv = b_kv[c + C_];
        #pragma unroll
        for (int n = 0; n < NH_; ++n) { ka[n] = bk; va[n] = bv; }
        #pragma unroll 4
        for (int cc = 0; cc < C_; ++cc) {
            const float w0 = Wkv[cc * C2_ + c];
            const float w1 = Wkv[cc * C2_ + c + C_];
            #pragma unroll
            for (int n = 0; n < NH_; ++n) {
                const float xv = sxn[grp][n][cc];
                ka[n] += xv * w0;
                va[n] += xv * w1;
            }
        }
    }
    // ---- kv = kv + kv @ W_nh  (mix across NH) ----
    {
        float k2[NH_], v2[NH_];
        #pragma unroll
        for (int m = 0; m < NH_; ++m) {
            float accK = ka[m], accV = va[m];
            #pragma unroll
            for (int n = 0; n < NH_; ++n) {
                const float w = swnh[n * NH_ + m];
                accK += ka[n] * w;
                accV += va[n] * w;
            }
            k2[m] = accK; v2[m] = accV;
        }
        #pragma unroll
        for (int n = 0; n < NH_; ++n) {
            sk_[grp][n][c] = k2[n];
            sv_[grp][n][c] = v2[n];
        }
    }
    __syncthreads();

    // ---- scores[h][n] = qh . kh / sqrt(DH), masked ----
    if (c < H_ * NH_) {
        const int h = c / NH_;
        const int n = c % NH_;
        float acc = 0.0f;
        #pragma unroll
        for (int dd = 0; dd < DH_; ++dd)
            acc += sq_[grp][h * DH_ + dd] * sk_[grp][n][h * DH_ + dd];
        acc *= 0.17677669529663687f;  // 1/sqrt(32)
        if (smsk[grp][n] != 0.0f) acc = -1e9f;
        sat[grp][h][n] = acc;
    }
    __syncthreads();

    // ---- softmax over n (9), one thread per head ----
    if (c < H_) {
        const int h = c;
        float mx = -INFINITY;
        #pragma unroll
        for (int n = 0; n < NH_; ++n) mx = fmaxf(mx, sat[grp][h][n]);
        float e[NH_]; float se = 0.0f;
        #pragma unroll
        for (int n = 0; n < NH_; ++n) { e[n] = expf(sat[grp][h][n] - mx); se += e[n]; }
        const float inv = 1.0f / se;
        #pragma unroll
        for (int n = 0; n < NH_; ++n) sat[grp][h][n] = e[n] * inv;
    }
    __syncthreads();

    // ---- o[c] = sum_n attn[h][n] * v[n][c] ----
    {
        const int h = c >> 5;
        float acc = 0.0f;
        #pragma unroll
        for (int n = 0; n < NH_; ++n) acc += sat[grp][h][n] * sv_[grp][n][c];
        sbuf[grp][c] = acc;
    }
    __syncthreads();

    // ---- ao = o @ W_ao ; x1 = x + ao ----
    float x1;
    {
        float acc = 0.0f;
        #pragma unroll 8
        for (int cc = 0; cc < C_; ++cc) acc += sbuf[grp][cc] * W_ao[cc * C_ + c];
        x1 = xc + acc;
    }

    // ---- LN2 over x1 ----
    {
        float s0 = x1, s1 = x1 * x1;
        #pragma unroll
        for (int off = 32; off; off >>= 1) {
            s0 += __shfl_down(s0, off, 64);
            s1 += __shfl_down(s1, off, 64);
        }
        const int wig = (threadIdx.x >> 6) & 1;
        if ((threadIdx.x & 63) == 0) { sred[grp][wig][0] = s0; sred[grp][wig][1] = s1; }
    }
    __syncthreads();
    {
        float sum = sred[grp][0][0] + sred[grp][1][0];
        float sq  = sred[grp][0][1] + sred[grp][1][1];
        float mean = sum * (1.0f / C_);
        float var  = sq  * (1.0f / C_) - mean * mean;
        float inv  = rsqrtf(var + 1e-5f);
        svec[grp][c] = (x1 - mean) * inv * ln2_g[c] + ln2_b[c];  // xm
    }
    __syncthreads();

    // ---- h = gelu(xm @ W1 + b1) ; thread owns cols c and c+128 ----
    {
        float a0 = b1[c];
        float a1 = b1[c + C_];
        #pragma unroll 4
        for (int cc = 0; cc < C_; ++cc) {
            const float xv = svec[grp][cc];
            a0 += xv * W1[cc * C2_ + c];
            a1 += xv * W1[cc * C2_ + c + C_];
        }
        sbuf[grp][c]      = gelu_tanh(a0);
        sbuf[grp][c + C_] = gelu_tanh(a1);
    }
    __syncthreads();

    // ---- y = x1 + gamma * (h @ W2 + b2) ----
    float y;
    {
        float acc = b2[c];
        #pragma unroll 8
        for (int e = 0; e < C2_; ++e) acc += sbuf[grp][e] * W2[e * C_ + c];
        y = x1 + gamma[c] * acc;
    }
    svec[grp][c] = y;
    __syncthreads();

    // ---- out = y @ Wout ----
    {
        float acc = 0.0f;
        #pragma unroll 8
        for (int cc = 0; cc < C_; ++cc) acc += svec[grp][cc] * Wout[cc * C_ + c];
        out[(size_t)tok * C_ + c] = acc;
    }
}

} // namespace

extern "C" void kernel_launch(void* const* d_in, const int* in_sizes, int n_in,
                              void* d_out, int out_size, void* d_ws, size_t ws_size,
                              hipStream_t stream) {
    const float* x     = (const float*)d_in[0];
    const int*   adjc  = (const int*)d_in[1];
    const unsigned char* mask = (const unsigned char*)d_in[2];
    const float* ln1_g = (const float*)d_in[3];
    const float* ln1_b = (const float*)d_in[4];
    const float* Wq    = (const float*)d_in[5];
    const float* Wkv   = (const float*)d_in[6];
    const float* b_kv  = (const float*)d_in[7];
    const float* W_nh  = (const float*)d_in[8];
    const float* W_ao  = (const float*)d_in[9];
    const float* ln2_g = (const float*)d_in[10];
    const float* ln2_b = (const float*)d_in[11];
    const float* W1    = (const float*)d_in[12];
    const float* b1    = (const float*)d_in[13];
    const float* W2    = (const float*)d_in[14];
    const float* b2    = (const float*)d_in[15];
    const float* gamma = (const float*)d_in[16];
    const float* Wout  = (const float*)d_in[17];
    float* out = (float*)d_out;
    float* xe  = (float*)d_ws;   // 65536*128 floats = 32 MB

    dim3 block(256);
    dim3 grid(NTOK / 2);
    ln1_kernel<<<grid, block, 0, stream>>>(x, ln1_g, ln1_b, xe);
    token_kernel<<<grid, block, 0, stream>>>(x, adjc, mask, Wq, Wkv, b_kv, W_nh,
                                             W_ao, ln2_g, ln2_b, W1, b1, W2, b2,
                                             gamma, Wout, xe, out);
}

// Round 2
// 216.119 us; speedup vs baseline: 6.0102x; 6.0102x over previous
//
#include <hip/hip_runtime.h>
#include <math.h>

namespace {

typedef float f32x4 __attribute__((ext_vector_type(4)));
typedef short s16x8 __attribute__((ext_vector_type(8)));

constexpr int C_   = 128;
constexpr int S_   = 16384;
constexpr int NTOK = 65536; // B*V*T*S

__device__ __forceinline__ unsigned short f2bf(float f) {
    unsigned int u = __float_as_uint(f);
    unsigned int r = (u + 0x7FFFu + ((u >> 16) & 1u)) >> 16;
    return (unsigned short)r;
}
__device__ __forceinline__ float bf2f(unsigned short h) {
    return __uint_as_float(((unsigned int)h) << 16);
}
__device__ __forceinline__ float gelu_tanh(float v) {
    const float k0 = 0.7978845608028654f;
    float u = k0 * (v + 0.044715f * v * v * v);
    return 0.5f * v * (1.0f + tanhf(u));
}

// ---------------------------------------------------------------------------
// Prep: pack weights into MFMA B-fragment order, bf16.
// frag layout per GEMM (K x N): idx = ((nt*KB + kb)*64 + lane)*8 + j
//   k = kb*32 + (lane>>4)*8 + j ; col = nt*16 + (lane&15)
// segments in Wf (ushort units):
//   [0]      qkv  K=128 N=384 (cols 0..127 Wq, 128..383 Wkv)
//   [49152]  ao   K=128 N=128
//   [65536]  W1   K=128 N=256
//   [98304]  W2   K=256 N=128
//   [131072] Wout K=128 N=128   (total 147456 ushorts)
// ---------------------------------------------------------------------------
__global__ __launch_bounds__(256) void prep_weights(
    const float* __restrict__ Wq, const float* __restrict__ Wkv,
    const float* __restrict__ W_ao, const float* __restrict__ W1,
    const float* __restrict__ W2, const float* __restrict__ Wout,
    unsigned short* __restrict__ Wf)
{
    int idx = blockIdx.x * 256 + threadIdx.x;
    if (idx >= 147456) return;
    int seg, off, K, N; const float* src = nullptr;
    if (idx < 49152)       { seg = 0; off = 0;      K = 128; N = 384; }
    else if (idx < 65536)  { seg = 1; off = 49152;  K = 128; N = 128; src = W_ao; }
    else if (idx < 98304)  { seg = 2; off = 65536;  K = 128; N = 256; src = W1; }
    else if (idx < 131072) { seg = 3; off = 98304;  K = 256; N = 128; src = W2; }
    else                   { seg = 4; off = 131072; K = 128; N = 128; src = Wout; }
    int local = idx - off;
    int j    = local & 7;
    int lane = (local >> 3) & 63;
    int tl   = local >> 9;
    int KB   = K >> 5;
    int kb   = tl % KB;
    int nt   = tl / KB;
    int k    = kb * 32 + ((lane >> 4) << 3) + j;
    int col  = (nt << 4) + (lane & 15);
    float v;
    if (seg == 0) v = (col < 128) ? Wq[k * 128 + col] : Wkv[k * 256 + (col - 128)];
    else          v = src[k * N + col];
    Wf[idx] = f2bf(v);
}

// ---------------------------------------------------------------------------
// Kernel A: LN1 + [q | kv] projection.  M-tile = 64 tokens, 4 waves.
// q (fp32) -> d_out ; kv (+b_kv, bf16) -> ws kv buffer.
// ---------------------------------------------------------------------------
__global__ __launch_bounds__(256, 2) void qkv_kernel(
    const float* __restrict__ x,
    const float* __restrict__ ln1_g, const float* __restrict__ ln1_b,
    const unsigned short* __restrict__ Wf,
    const float* __restrict__ b_kv,
    float* qout, unsigned short* __restrict__ kvout)
{
    __shared__ unsigned short xet[64 * 128]; // bf16, XOR-swizzled, 16KB
    const int tile = blockIdx.x;
    const int t = threadIdx.x;

    // ---- phase 1: LN1, write xe tile (bf16, swizzled) ----
    {
        const int row = t >> 2;       // 0..63
        const int q4  = t & 3;        // quarter of the row
        const int tok = tile * 64 + row;
        const float* xr = x + (size_t)tok * C_ + q4 * 32;
        float v[32];
        float s0 = 0.f, s1 = 0.f;
        #pragma unroll
        for (int i = 0; i < 32; i += 4) {
            float4 f = *(const float4*)(xr + i);
            v[i] = f.x; v[i+1] = f.y; v[i+2] = f.z; v[i+3] = f.w;
            s0 += f.x + f.y + f.z + f.w;
            s1 += f.x*f.x + f.y*f.y + f.z*f.z + f.w*f.w;
        }
        s0 += __shfl_xor(s0, 1, 64); s1 += __shfl_xor(s1, 1, 64);
        s0 += __shfl_xor(s0, 2, 64); s1 += __shfl_xor(s1, 2, 64);
        const float mean = s0 * (1.0f / C_);
        const float var  = s1 * (1.0f / C_) - mean * mean;
        const float inv  = rsqrtf(var + 1e-5f);
        #pragma unroll
        for (int jj = 0; jj < 4; ++jj) {
            unsigned short tmp[8];
            #pragma unroll
            for (int j = 0; j < 8; ++j) {
                int k = q4 * 32 + jj * 8 + j;
                tmp[j] = f2bf((v[jj*8 + j] - mean) * inv * ln1_g[k] + ln1_b[k]);
            }
            int byte = row * 256 + (q4 * 32 + jj * 8) * 2;
            byte ^= (row & 7) << 4;
            *(s16x8*)((char*)xet + byte) = *(const s16x8*)tmp;
        }
    }
    __syncthreads();

    // ---- phase 2: MFMA GEMM  (M=64 x K=128) @ (K=128 x N=384) ----
    const int w = t >> 6, l = t & 63;
    const int arow = (w << 4) + (l & 15);
    s16x8 af[4];
    #pragma unroll
    for (int kb = 0; kb < 4; ++kb) {
        int byte = arow * 256 + (kb * 32 + ((l >> 4) << 3)) * 2;
        byte ^= (arow & 7) << 4;
        af[kb] = *(const s16x8*)((const char*)xet + byte);
    }
    f32x4 acc[24];
    #pragma unroll
    for (int nt = 0; nt < 24; ++nt) acc[nt] = (f32x4){0.f, 0.f, 0.f, 0.f};
    #pragma unroll
    for (int nt = 0; nt < 24; ++nt) {
        #pragma unroll
        for (int kb = 0; kb < 4; ++kb) {
            s16x8 bf = *(const s16x8*)(Wf + (size_t)((nt * 4 + kb) * 64 + l) * 8);
            acc[nt] = __builtin_amdgcn_mfma_f32_16x16x32_bf16(af[kb], bf, acc[nt], 0, 0, 0);
        }
    }
    // ---- epilogue ----
    const int r0 = (l >> 4) << 2;
    const int colb = l & 15;
    #pragma unroll
    for (int nt = 0; nt < 24; ++nt) {
        const int col = nt * 16 + colb;
        const float bias = (col >= 128) ? b_kv[col - 128] : 0.f;
        #pragma unroll
        for (int reg = 0; reg < 4; ++reg) {
            const size_t tokr = (size_t)tile * 64 + (w << 4) + r0 + reg;
            const float val = acc[nt][reg];
            if (col < 128) qout[tokr * 128 + col] = val;
            else           kvout[tokr * 256 + (col - 128)] = f2bf(val + bias);
        }
    }
}

// ---------------------------------------------------------------------------
// Kernel B: gather kv -> (I+W_nh) mix -> scores -> softmax -> PV -> o (bf16).
// 2 tokens per block, 128 threads each.  q read fp32 from d_out; o written
// bf16 into the first 256B of the token's d_out row.
// ---------------------------------------------------------------------------
__global__ __launch_bounds__(256) void attn_kernel(
    const int* __restrict__ adjc, const unsigned char* __restrict__ mask,
    const float* __restrict__ W_nh,
    const float* qbuf, const unsigned short* __restrict__ kv,
    unsigned short* obuf)
{
    __shared__ float sq[2][128];
    __shared__ float sk[2][9][128];
    __shared__ float sv[2][9][128];
    __shared__ float sat[2][4][9];
    __shared__ int   sidx[2][9];
    __shared__ float smsk[2][9];
    __shared__ float m2[81];      // I + W_nh

    const int grp = threadIdx.x >> 7;
    const int c   = threadIdx.x & 127;
    const int tok = blockIdx.x * 2 + grp;
    const int bvt = tok >> 14;
    const int s   = tok & (S_ - 1);

    if (threadIdx.x < 81)
        m2[threadIdx.x] = W_nh[threadIdx.x] + ((threadIdx.x % 10 == 0) ? 1.f : 0.f);
    if (c < 9) {
        int nb = adjc[s * 9 + c];
        int gi = bvt * S_ + nb;
        sidx[grp][c] = gi;
        smsk[grp][c] = mask[gi] ? 1.f : 0.f;
    }
    sq[grp][c] = qbuf[(size_t)tok * 128 + c];
    __syncthreads();

    float ka[9], va[9];
    #pragma unroll
    for (int n = 0; n < 9; ++n) {
        size_t o = (size_t)sidx[grp][n] * 256 + c;
        ka[n] = bf2f(kv[o]);
        va[n] = bf2f(kv[o + 128]);
    }
    #pragma unroll
    for (int m = 0; m < 9; ++m) {
        float aK = 0.f, aV = 0.f;
        #pragma unroll
        for (int n = 0; n < 9; ++n) {
            float wv = m2[n * 9 + m];
            aK += ka[n] * wv;
            aV += va[n] * wv;
        }
        sk[grp][m][c] = aK;
        sv[grp][m][c] = aV;
    }
    __syncthreads();

    if (c < 36) {
        const int h = c / 9, n = c % 9;
        float acc = 0.f;
        #pragma unroll
        for (int d = 0; d < 32; ++d)
            acc += sq[grp][h * 32 + d] * sk[grp][n][h * 32 + d];
        acc *= 0.17677669529663687f;
        if (smsk[grp][n] != 0.f) acc = -1e9f;
        sat[grp][h][n] = acc;
    }
    __syncthreads();

    if (c < 4) {
        const int h = c;
        float mx = -INFINITY;
        #pragma unroll
        for (int n = 0; n < 9; ++n) mx = fmaxf(mx, sat[grp][h][n]);
        float e[9], se = 0.f;
        #pragma unroll
        for (int n = 0; n < 9; ++n) { e[n] = expf(sat[grp][h][n] - mx); se += e[n]; }
        const float inv = 1.f / se;
        #pragma unroll
        for (int n = 0; n < 9; ++n) sat[grp][h][n] = e[n] * inv;
    }
    __syncthreads();

    {
        const int h = c >> 5;
        float acc = 0.f;
        #pragma unroll
        for (int n = 0; n < 9; ++n) acc += sat[grp][h][n] * sv[grp][n][c];
        obuf[(size_t)tok * 256 + c] = f2bf(acc);
    }
}

// ---------------------------------------------------------------------------
// Kernel C: fused epilogue. Tile of 64 tokens, 4 waves.
//  GEMM1 ao = o@W_ao ; x1 = x + ao ; LN2 (in-register row stats)
//  GEMM2 h = gelu(xm@W1 + b1) ; GEMM3 y = x1 + gamma*(h@W2 + b2)
//  GEMM4 out = y@Wout  -> d_out (fp32, overwrites o region)
// ---------------------------------------------------------------------------
__global__ __launch_bounds__(256, 2) void mlp_kernel(
    const float* __restrict__ x,
    const unsigned short* obuf,
    const unsigned short* __restrict__ Wao_f, const unsigned short* __restrict__ W1f,
    const unsigned short* __restrict__ W2f, const unsigned short* __restrict__ Woutf,
    const float* __restrict__ ln2_g, const float* __restrict__ ln2_b,
    const float* __restrict__ b1, const float* __restrict__ b2,
    const float* __restrict__ gamma,
    float* outp)
{
    __shared__ unsigned short act[16384]; // 32KB activation tile (xm / h / y)
    const int tile = blockIdx.x;
    const int t = threadIdx.x;
    const int w = t >> 6, l = t & 63;
    const int arow = (w << 4) + (l & 15);         // A-frag local row
    const int crow0 = (w << 4) + ((l >> 4) << 2); // C local row base
    const int colb = l & 15;
    const size_t base = (size_t)tile * 64;

    // ---- GEMM1: A = o (bf16 from d_out rows), B = W_ao ----
    s16x8 af[4];
    #pragma unroll
    for (int kb = 0; kb < 4; ++kb)
        af[kb] = *(const s16x8*)(obuf + (base + arow) * 256 + kb * 32 + ((l >> 4) << 3));
    f32x4 acc1[8];
    #pragma unroll
    for (int nt = 0; nt < 8; ++nt) acc1[nt] = (f32x4){0.f, 0.f, 0.f, 0.f};
    #pragma unroll
    for (int nt = 0; nt < 8; ++nt) {
        #pragma unroll
        for (int kb = 0; kb < 4; ++kb) {
            s16x8 bf = *(const s16x8*)(Wao_f + (size_t)((nt * 4 + kb) * 64 + l) * 8);
            acc1[nt] = __builtin_amdgcn_mfma_f32_16x16x32_bf16(af[kb], bf, acc1[nt], 0, 0, 0);
        }
    }

    // ---- x1 = x + ao ; LN2 row stats in-register ----
    float x1v[8][4];
    float ss[4] = {0.f, 0.f, 0.f, 0.f}, s2[4] = {0.f, 0.f, 0.f, 0.f};
    #pragma unroll
    for (int nt = 0; nt < 8; ++nt) {
        const int col = nt * 16 + colb;
        #pragma unroll
        for (int reg = 0; reg < 4; ++reg) {
            const size_t tokr = base + crow0 + reg;
            float xv = x[tokr * 128 + col] + acc1[nt][reg];
            x1v[nt][reg] = xv;
            ss[reg] += xv;
            s2[reg] += xv * xv;
        }
    }
    #pragma unroll
    for (int off = 1; off < 16; off <<= 1) {
        #pragma unroll
        for (int reg = 0; reg < 4; ++reg) {
            ss[reg] += __shfl_xor(ss[reg], off, 64);
            s2[reg] += __shfl_xor(s2[reg], off, 64);
        }
    }
    float mean[4], inv[4];
    #pragma unroll
    for (int reg = 0; reg < 4; ++reg) {
        mean[reg] = ss[reg] * (1.0f / 128.f);
        float var = s2[reg] * (1.0f / 128.f) - mean[reg] * mean[reg];
        inv[reg] = rsqrtf(var + 1e-5f);
    }
    // xm -> LDS (bf16, swizzled)
    #pragma unroll
    for (int nt = 0; nt < 8; ++nt) {
        const int col = nt * 16 + colb;
        const float lg = ln2_g[col], lb = ln2_b[col];
        #pragma unroll
        for (int reg = 0; reg < 4; ++reg) {
            const int lrow = crow0 + reg;
            float xm = (x1v[nt][reg] - mean[reg]) * inv[reg] * lg + lb;
            int byte = lrow * 256 + col * 2;
            byte ^= (lrow & 7) << 4;
            *(unsigned short*)((char*)act + byte) = f2bf(xm);
        }
    }
    __syncthreads();

    // ---- GEMM2: h = gelu(xm @ W1 + b1), N=256 ----
    #pragma unroll
    for (int kb = 0; kb < 4; ++kb) {
        int byte = arow * 256 + (kb * 32 + ((l >> 4) << 3)) * 2;
        byte ^= (arow & 7) << 4;
        af[kb] = *(const s16x8*)((const char*)act + byte);
    }
    f32x4 acc2[16];
    #pragma unroll
    for (int nt = 0; nt < 16; ++nt) acc2[nt] = (f32x4){0.f, 0.f, 0.f, 0.f};
    #pragma unroll
    for (int nt = 0; nt < 16; ++nt) {
        #pragma unroll
        for (int kb = 0; kb < 4; ++kb) {
            s16x8 bf = *(const s16x8*)(W1f + (size_t)((nt * 4 + kb) * 64 + l) * 8);
            acc2[nt] = __builtin_amdgcn_mfma_f32_16x16x32_bf16(af[kb], bf, acc2[nt], 0, 0, 0);
        }
    }
    __syncthreads();   // all xm reads done before overwriting act with h
    #pragma unroll
    for (int nt = 0; nt < 16; ++nt) {
        const int col2 = nt * 16 + colb;
        const float bb = b1[col2];
        #pragma unroll
        for (int reg = 0; reg < 4; ++reg) {
            const int lrow = crow0 + reg;
            float hv = gelu_tanh(acc2[nt][reg] + bb);
            int byte = lrow * 512 + col2 * 2;
            byte ^= (lrow & 7) << 4;
            *(unsigned short*)((char*)act + byte) = f2bf(hv);
        }
    }
    __syncthreads();

    // ---- GEMM3: z = h @ W2 (K=256) ; y = x1 + gamma*(z + b2) ----
    f32x4 acc3[8];
    #pragma unroll
    for (int nt = 0; nt < 8; ++nt) acc3[nt] = (f32x4){0.f, 0.f, 0.f, 0.f};
    #pragma unroll
    for (int kb = 0; kb < 8; ++kb) {
        int byte = arow * 512 + (kb * 32 + ((l >> 4) << 3)) * 2;
        byte ^= (arow & 7) << 4;
        s16x8 hf = *(const s16x8*)((const char*)act + byte);
        #pragma unroll
        for (int nt = 0; nt < 8; ++nt) {
            s16x8 bf = *(const s16x8*)(W2f + (size_t)((nt * 8 + kb) * 64 + l) * 8);
            acc3[nt] = __builtin_amdgcn_mfma_f32_16x16x32_bf16(hf, bf, acc3[nt], 0, 0, 0);
        }
    }
    __syncthreads();   // all h reads done before overwriting act with y
    #pragma unroll
    for (int nt = 0; nt < 8; ++nt) {
        const int col = nt * 16 + colb;
        const float gm = gamma[col], bb = b2[col];
        #pragma unroll
        for (int reg = 0; reg < 4; ++reg) {
            const int lrow = crow0 + reg;
            float y = x1v[nt][reg] + gm * (acc3[nt][reg] + bb);
            int byte = lrow * 256 + col * 2;
            byte ^= (lrow & 7) << 4;
            *(unsigned short*)((char*)act + byte) = f2bf(y);
        }
    }
    __syncthreads();

    // ---- GEMM4: out = y @ Wout ----
    #pragma unroll
    for (int kb = 0; kb < 4; ++kb) {
        int byte = arow * 256 + (kb * 32 + ((l >> 4) << 3)) * 2;
        byte ^= (arow & 7) << 4;
        af[kb] = *(const s16x8*)((const char*)act + byte);
    }
    f32x4 acc4[8];
    #pragma unroll
    for (int nt = 0; nt < 8; ++nt) acc4[nt] = (f32x4){0.f, 0.f, 0.f, 0.f};
    #pragma unroll
    for (int nt = 0; nt < 8; ++nt) {
        #pragma unroll
        for (int kb = 0; kb < 4; ++kb) {
            s16x8 bf = *(const s16x8*)(Woutf + (size_t)((nt * 4 + kb) * 64 + l) * 8);
            acc4[nt] = __builtin_amdgcn_mfma_f32_16x16x32_bf16(af[kb], bf, acc4[nt], 0, 0, 0);
        }
    }
    #pragma unroll
    for (int nt = 0; nt < 8; ++nt) {
        const int col = nt * 16 + colb;
        #pragma unroll
        for (int reg = 0; reg < 4; ++reg) {
            const size_t tokr = base + crow0 + reg;
            outp[tokr * 128 + col] = acc4[nt][reg];
        }
    }
}

} // namespace

extern "C" void kernel_launch(void* const* d_in, const int* in_sizes, int n_in,
                              void* d_out, int out_size, void* d_ws, size_t ws_size,
                              hipStream_t stream) {
    const float* x     = (const float*)d_in[0];
    const int*   adjc  = (const int*)d_in[1];
    const unsigned char* mask = (const unsigned char*)d_in[2];
    const float* ln1_g = (const float*)d_in[3];
    const float* ln1_b = (const float*)d_in[4];
    const float* Wq    = (const float*)d_in[5];
    const float* Wkv   = (const float*)d_in[6];
    const float* b_kv  = (const float*)d_in[7];
    const float* W_nh  = (const float*)d_in[8];
    const float* W_ao  = (const float*)d_in[9];
    const float* ln2_g = (const float*)d_in[10];
    const float* ln2_b = (const float*)d_in[11];
    const float* W1    = (const float*)d_in[12];
    const float* b1    = (const float*)d_in[13];
    const float* W2    = (const float*)d_in[14];
    const float* b2    = (const float*)d_in[15];
    const float* gamma = (const float*)d_in[16];
    const float* Wout  = (const float*)d_in[17];

    // ws layout: [0, 32MiB): kv bf16 (65536 x 256); then fragment weights.
    unsigned short* kv = (unsigned short*)d_ws;
    unsigned short* Wf = (unsigned short*)((char*)d_ws + (size_t)NTOK * 256 * 2);
    unsigned short* Wao_f  = Wf + 49152;
    unsigned short* W1f    = Wf + 65536;
    unsigned short* W2f    = Wf + 98304;
    unsigned short* Woutf  = Wf + 131072;

    float*          qbuf = (float*)d_out;          // q fp32, then o bf16, then out
    unsigned short* obuf = (unsigned short*)d_out;

    prep_weights<<<576, 256, 0, stream>>>(Wq, Wkv, W_ao, W1, W2, Wout, Wf);
    qkv_kernel<<<NTOK / 64, 256, 0, stream>>>(x, ln1_g, ln1_b, Wf, b_kv, qbuf, kv);
    attn_kernel<<<NTOK / 2, 256, 0, stream>>>(adjc, mask, W_nh, qbuf, kv, obuf);
    mlp_kernel<<<NTOK / 64, 256, 0, stream>>>(x, obuf, Wao_f, W1f, W2f, Woutf,
                                              ln2_g, ln2_b, b1, b2, gamma,
                                              (float*)d_out);
}